// Round 1
// baseline (560.701 us; speedup 1.0000x reference)
//
#include <hip/hip_runtime.h>
#include <math.h>

#define B_   128
#define R_   1152
#define C_   16
#define O_   16
#define I_   8
#define NSPLIT 8
#define RCHUNK (R_ / NSPLIT)   // 144

// ---------------- softmax over routes axis (axis 0 of [R,C]) ----------------
__global__ void softmax_k(const float* __restrict__ blog, float* __restrict__ cw) {
    const int c = blockIdx.x;      // 0..15
    const int t = threadIdx.x;     // 0..255
    __shared__ float red[256];

    float m = -1e30f;
    for (int r = t; r < R_; r += 256) m = fmaxf(m, blog[r * C_ + c]);
    red[t] = m; __syncthreads();
    for (int s = 128; s > 0; s >>= 1) {
        if (t < s) red[t] = fmaxf(red[t], red[t + s]);
        __syncthreads();
    }
    const float M = red[0]; __syncthreads();

    float e = 0.f;
    for (int r = t; r < R_; r += 256) e += expf(blog[r * C_ + c] - M);
    red[t] = e; __syncthreads();
    for (int s = 128; s > 0; s >>= 1) {
        if (t < s) red[t] += red[t + s];
        __syncthreads();
    }
    const float inv = 1.0f / red[0];

    for (int r = t; r < R_; r += 256) cw[r * C_ + c] = expf(blog[r * C_ + c] - M) * inv;
}

// ---------------- s partials: s[b,c,o] = sum_r cw[r,c] * sum_i W[r,c,o,i]*x[b,r,i] ----
// grid (C_, 8 b-tiles, NSPLIT r-chunks), 256 threads: thread owns (b, o).
__global__ void s_part_k(const float* __restrict__ x, const float* __restrict__ W,
                         const float* __restrict__ cw, float* __restrict__ sp) {
    const int c  = blockIdx.x;
    const int bt = blockIdx.y;
    const int rc = blockIdx.z;
    const int t  = threadIdx.x;
    const int o  = t & 15;
    const int b  = bt * 16 + (t >> 4);

    const float4* __restrict__ W4 = (const float4*)W;
    const float4* __restrict__ X4 = (const float4*)x;

    float acc = 0.f;
    const int r0 = rc * RCHUNK;
    #pragma unroll 4
    for (int r = r0; r < r0 + RCHUNK; ++r) {
        const float cr = cw[r * C_ + c];                  // wave-uniform -> s_load
        const int wbase = ((r * C_ + c) * O_ + o) * 2;    // float4 index
        const float4 w0 = W4[wbase];
        const float4 w1 = W4[wbase + 1];
        const int xbase = (b * R_ + r) * 2;
        const float4 x0 = X4[xbase];
        const float4 x1 = X4[xbase + 1];
        float dot = w0.x * x0.x + w0.y * x0.y + w0.z * x0.z + w0.w * x0.w
                  + w1.x * x1.x + w1.y * x1.y + w1.z * x1.z + w1.w * x1.w;
        acc = fmaf(cr, dot, acc);
    }
    sp[rc * (B_ * C_ * O_) + (b * C_ + c) * O_ + o] = acc;
}

// ---------------- reduce partials + squash: v = s*|s|/(1+s^2) ----------------
__global__ void reduce_squash_k(const float* __restrict__ sp, float* __restrict__ v) {
    const int idx = blockIdx.x * 256 + threadIdx.x;
    float s = 0.f;
    #pragma unroll
    for (int k = 0; k < NSPLIT; ++k) s += sp[k * (B_ * C_ * O_) + idx];
    v[idx] = s * fabsf(s) / (1.0f + s * s);
}

// ---------------- a-update: blog[r,c] += (1/B) sum_{b,o} uhat[b,r,c,o]*v[b,c,o] -----
// block per r, 256 threads: thread = (c = t>>4, g = t&15), g strides over b.
__global__ void a_update_k(const float* __restrict__ x, const float* __restrict__ W,
                           const float* __restrict__ v, float* __restrict__ blog) {
    const int r = blockIdx.x;
    const int t = threadIdx.x;
    const int c = t >> 4;
    const int g = t & 15;

    __shared__ float Wl[C_ * 132];   // per-c row padded 128 -> 132 floats (bank spread)
    {
        const float4* __restrict__ W4 = (const float4*)W;
        #pragma unroll
        for (int k = 0; k < 2; ++k) {
            const int idx4 = t + k * 256;          // 0..511 float4s of W[r,:,:,:]
            const float4 wv = W4[r * 512 + idx4];
            const int cl  = idx4 >> 5;             // which c row
            const int off = (idx4 & 31) * 4;       // float offset in row
            *((float4*)&Wl[cl * 132 + off]) = wv;
        }
    }
    __syncthreads();

    const float4* __restrict__ X4 = (const float4*)x;
    const float4* __restrict__ V4 = (const float4*)v;
    const float4* __restrict__ Wc = (const float4*)&Wl[c * 132];

    float acc = 0.f;
    #pragma unroll 2
    for (int k = 0; k < 8; ++k) {
        const int b = g + k * 16;
        const int xbase = (b * R_ + r) * 2;
        const float4 x0 = X4[xbase];
        const float4 x1 = X4[xbase + 1];
        const int vbase = (b * C_ + c) * 4;        // float4 index of v[b,c,0]
        const float4 va = V4[vbase];
        const float4 vb = V4[vbase + 1];
        const float4 vc = V4[vbase + 2];
        const float4 vd = V4[vbase + 3];
        const float vv[16] = {va.x, va.y, va.z, va.w, vb.x, vb.y, vb.z, vb.w,
                              vc.x, vc.y, vc.z, vc.w, vd.x, vd.y, vd.z, vd.w};
        #pragma unroll
        for (int o = 0; o < 16; ++o) {
            const float4 w0 = Wc[o * 2];
            const float4 w1 = Wc[o * 2 + 1];
            float dot = w0.x * x0.x + w0.y * x0.y + w0.z * x0.z + w0.w * x0.w
                      + w1.x * x1.x + w1.y * x1.y + w1.z * x1.z + w1.w * x1.w;
            acc = fmaf(dot, vv[o], acc);
        }
    }

    __shared__ float red[256];
    red[t] = acc; __syncthreads();
    for (int s = 8; s > 0; s >>= 1) {
        if (g < s) red[t] += red[t + s];
        __syncthreads();
    }
    if (g == 0) blog[r * C_ + c] += red[c * 16] * (1.0f / (float)B_);
}

extern "C" void kernel_launch(void* const* d_in, const int* in_sizes, int n_in,
                              void* d_out, int out_size, void* d_ws, size_t ws_size,
                              hipStream_t stream) {
    const float* x = (const float*)d_in[0];   // [128,1152,8]
    const float* W = (const float*)d_in[1];   // [1,1152,16,16,8]
    float* out = (float*)d_out;               // [128,16,16]
    float* ws  = (float*)d_ws;

    float* blog = ws;                         // R*C = 18432
    float* cwv  = ws + 18432;                 // R*C = 18432
    float* sp   = ws + 36864;                 // NSPLIT * 32768 = 262144
    float* vbuf = ws + 299008;                // 32768
    // total ws use: 331776 floats = 1.27 MB

    hipMemsetAsync(blog, 0, R_ * C_ * sizeof(float), stream);

    for (int it = 0; it < 3; ++it) {
        softmax_k<<<C_, 256, 0, stream>>>(blog, cwv);
        s_part_k<<<dim3(C_, 8, NSPLIT), 256, 0, stream>>>(x, W, cwv, sp);
        float* vout = (it == 2) ? out : vbuf;
        reduce_squash_k<<<(B_ * C_ * O_) / 256, 256, 0, stream>>>(sp, vout);
        if (it < 2) a_update_k<<<R_, 256, 0, stream>>>(x, W, vout, blog);
    }
}

// Round 2
// 303.748 us; speedup vs baseline: 1.8459x; 1.8459x over previous
//
#include <hip/hip_runtime.h>
#include <math.h>

#define B_   128
#define R_   1152
#define C_   16
#define O_   16
#define I_   8

// ---------------- softmax over routes axis (axis 0 of [R,C]) ----------------
__global__ void softmax_k(const float* __restrict__ blog, float* __restrict__ cw) {
    const int c = blockIdx.x;      // 0..15
    const int t = threadIdx.x;     // 0..255
    __shared__ float red[256];

    float m = -1e30f;
    for (int r = t; r < R_; r += 256) m = fmaxf(m, blog[r * C_ + c]);
    red[t] = m; __syncthreads();
    for (int s = 128; s > 0; s >>= 1) {
        if (t < s) red[t] = fmaxf(red[t], red[t + s]);
        __syncthreads();
    }
    const float M = red[0]; __syncthreads();

    float e = 0.f;
    for (int r = t; r < R_; r += 256) e += expf(blog[r * C_ + c] - M);
    red[t] = e; __syncthreads();
    for (int s = 128; s > 0; s >>= 1) {
        if (t < s) red[t] += red[t + s];
        __syncthreads();
    }
    const float inv = 1.0f / red[0];

    for (int r = t; r < R_; r += 256) cw[r * C_ + c] = expf(blog[r * C_ + c] - M) * inv;
}

// ---------------- GEMM1: s_partial[rs][b][co] = sum_{r in chunk, i} x[b,r,i]*cw[r,c]*W[r,co,i]
// grid (8 b-tiles, RS k-splits), 256 threads. Thread: co4 = t&63 (4 consecutive co),
// b4 = t>>6 (4 consecutive b). All lanes of a wave share b4 -> x LDS reads broadcast.
// W streamed from global, fully coalesced (wave covers all 256 co).
__global__ void gemm1_k(const float* __restrict__ x, const float* __restrict__ W,
                        const float* __restrict__ cw, float* __restrict__ sp,
                        int rchunk) {
    const int bt  = blockIdx.x;           // 0..7
    const int rs  = blockIdx.y;           // 0..RS-1
    const int t   = threadIdx.x;
    const int co4 = t & 63;               // co base = co4*4
    const int b4  = t >> 6;               // b base (local) = b4*4
    const int c   = co4 >> 2;             // capsule index (same for the 4 co)
    const int r0  = rs * rchunk;

    __shared__ float xl[16 * 12 * 8];     // 16 b x 12 r x 8 i = 6 KB
    float4* xl4 = (float4*)xl;

    const float4* __restrict__ X4 = (const float4*)x;
    const float4* __restrict__ W4 = (const float4*)W;

    float acc[4][4];
    #pragma unroll
    for (int j = 0; j < 4; ++j)
        #pragma unroll
        for (int q = 0; q < 4; ++q) acc[j][q] = 0.f;

    const int ngroups = rchunk / 12;
    for (int g = 0; g < ngroups; ++g) {
        const int rg0 = r0 + g * 12;
        __syncthreads();
        // stage x[bt*16 + bl][rg0..rg0+11][0:8] -> 384 float4
        {
            int u = t;
            if (u < 384) {
                const int bl = u / 24, rem = u % 24;
                xl4[u] = X4[((bt * 16 + bl) * R_ + rg0) * 2 + rem];
            }
            u = t + 256;
            if (u < 384) {
                const int bl = u / 24, rem = u % 24;
                xl4[u] = X4[((bt * 16 + bl) * R_ + rg0) * 2 + rem];
            }
        }
        __syncthreads();

        #pragma unroll 3
        for (int rr = 0; rr < 12; ++rr) {
            const int r = rg0 + rr;
            const float cwv = cw[r * C_ + c];
            // W[r][co4*4 .. +3][0:8] = 8 float4
            const int wb = r * 512 + co4 * 8;
            float4 w0 = W4[wb + 0], w1 = W4[wb + 1], w2 = W4[wb + 2], w3 = W4[wb + 3];
            float4 w4 = W4[wb + 4], w5 = W4[wb + 5], w6 = W4[wb + 6], w7 = W4[wb + 7];
            #pragma unroll
            for (int j = 0; j < 4; ++j) {
                const int bl = b4 * 4 + j;
                const float4 xa = xl4[bl * 24 + rr * 2];
                const float4 xb = xl4[bl * 24 + rr * 2 + 1];
                float d0 = w0.x*xa.x + w0.y*xa.y + w0.z*xa.z + w0.w*xa.w
                         + w1.x*xb.x + w1.y*xb.y + w1.z*xb.z + w1.w*xb.w;
                float d1 = w2.x*xa.x + w2.y*xa.y + w2.z*xa.z + w2.w*xa.w
                         + w3.x*xb.x + w3.y*xb.y + w3.z*xb.z + w3.w*xb.w;
                float d2 = w4.x*xa.x + w4.y*xa.y + w4.z*xa.z + w4.w*xa.w
                         + w5.x*xb.x + w5.y*xb.y + w5.z*xb.z + w5.w*xb.w;
                float d3 = w6.x*xa.x + w6.y*xa.y + w6.z*xa.z + w6.w*xa.w
                         + w7.x*xb.x + w7.y*xb.y + w7.z*xb.z + w7.w*xb.w;
                acc[j][0] = fmaf(cwv, d0, acc[j][0]);
                acc[j][1] = fmaf(cwv, d1, acc[j][1]);
                acc[j][2] = fmaf(cwv, d2, acc[j][2]);
                acc[j][3] = fmaf(cwv, d3, acc[j][3]);
            }
        }
    }

    float4* sp4 = (float4*)sp;
    #pragma unroll
    for (int j = 0; j < 4; ++j) {
        const int b = bt * 16 + b4 * 4 + j;
        float4 o; o.x = acc[j][0]; o.y = acc[j][1]; o.z = acc[j][2]; o.w = acc[j][3];
        sp4[(rs * B_ + b) * 64 + co4] = o;
    }
}

// ---------------- reduce split-K partials + squash: v = s*|s|/(1+s^2) ----------------
__global__ void reduce_squash_k(const float* __restrict__ sp, float* __restrict__ v, int RS) {
    const int b = blockIdx.x;
    const int t = threadIdx.x;
    float s = 0.f;
    for (int k = 0; k < RS; ++k) s += sp[(k * B_ + b) * 256 + t];
    v[b * 256 + t] = s * fabsf(s) / (1.0f + s * s);
}

// ---------------- a-update via Y = x^T v factorization ----------------
// block = 4 r's, wave w owns r = blockIdx*4 + w. Lane co4 holds Y[r][i=0:8][co4*4..+3]
// in regs (32 acc), K-loop over b=0..127 (x from LDS broadcast, v coalesced global).
// Epilogue: contract with W[r] (coalesced 8KB/wave), 4-lane shuffle reduce, blog += a/B.
__global__ void a_fused_k(const float* __restrict__ x, const float* __restrict__ W,
                          const float* __restrict__ v, float* __restrict__ blog) {
    const int r0  = blockIdx.x * 4;
    const int t   = threadIdx.x;
    const int rr  = t >> 6;               // wave id = local r
    const int co4 = t & 63;
    const int c   = co4 >> 2;
    const int r   = r0 + rr;

    __shared__ float xl[128 * 4 * 8];     // [b][rr][i] = 16 KB
    float4* xl4 = (float4*)xl;
    const float4* __restrict__ X4 = (const float4*)x;
    const float4* __restrict__ V4 = (const float4*)v;
    const float4* __restrict__ W4 = (const float4*)W;

    // stage x[b][r0..r0+3][0:8]: per b 8 contiguous float4
    #pragma unroll
    for (int k = 0; k < 4; ++k) {
        const int u = t + k * 256;        // 0..1023
        const int b = u >> 3, rem = u & 7;
        xl4[u] = X4[(b * R_ + r0) * 2 + rem];
    }
    __syncthreads();

    float y[8][4];
    #pragma unroll
    for (int i = 0; i < 8; ++i)
        #pragma unroll
        for (int q = 0; q < 4; ++q) y[i][q] = 0.f;

    #pragma unroll 4
    for (int b = 0; b < B_; ++b) {
        const float4 xa = xl4[b * 8 + rr * 2];
        const float4 xb = xl4[b * 8 + rr * 2 + 1];
        const float4 vv = V4[b * 64 + co4];
        const float xs[8] = {xa.x, xa.y, xa.z, xa.w, xb.x, xb.y, xb.z, xb.w};
        #pragma unroll
        for (int i = 0; i < 8; ++i) {
            y[i][0] = fmaf(xs[i], vv.x, y[i][0]);
            y[i][1] = fmaf(xs[i], vv.y, y[i][1]);
            y[i][2] = fmaf(xs[i], vv.z, y[i][2]);
            y[i][3] = fmaf(xs[i], vv.w, y[i][3]);
        }
    }

    // epilogue: part = sum_{q,i} W[r, co4*4+q, i] * y[i][q]
    const int wb = r * 512 + co4 * 8;     // float4 base of W[r][co4*4][0]
    float part = 0.f;
    #pragma unroll
    for (int q = 0; q < 4; ++q) {
        const float4 w0 = W4[wb + q * 2];
        const float4 w1 = W4[wb + q * 2 + 1];
        part += w0.x*y[0][q] + w0.y*y[1][q] + w0.z*y[2][q] + w0.w*y[3][q]
              + w1.x*y[4][q] + w1.y*y[5][q] + w1.z*y[6][q] + w1.w*y[7][q];
    }
    part += __shfl_xor(part, 1);
    part += __shfl_xor(part, 2);
    if ((co4 & 3) == 0) blog[r * C_ + c] += part * (1.0f / (float)B_);
}

extern "C" void kernel_launch(void* const* d_in, const int* in_sizes, int n_in,
                              void* d_out, int out_size, void* d_ws, size_t ws_size,
                              hipStream_t stream) {
    const float* x = (const float*)d_in[0];   // [128,1152,8]
    const float* W = (const float*)d_in[1];   // [1,1152,16,16,8]
    float* out = (float*)d_out;               // [128,16,16]
    float* ws  = (float*)d_ws;

    // pick split-K count by available workspace (divisors of 96 -> rchunk % 12 == 0)
    int RS = 96;
    const size_t fixed_b = (size_t)(18432 + 18432 + 32768) * 4;
    while (RS > 6 && (size_t)RS * (B_ * 256 * 4) + fixed_b > ws_size) RS >>= 1;
    const int rchunk = R_ / RS;

    float* blog = ws;                         // R*C = 18432
    float* cwv  = ws + 18432;                 // R*C = 18432
    float* vbuf = ws + 36864;                 // 32768
    float* sp   = ws + 69632;                 // RS * 32768

    hipMemsetAsync(blog, 0, R_ * C_ * sizeof(float), stream);

    for (int it = 0; it < 3; ++it) {
        softmax_k<<<C_, 256, 0, stream>>>(blog, cwv);
        gemm1_k<<<dim3(8, RS), 256, 0, stream>>>(x, W, cwv, sp, rchunk);
        float* vout = (it == 2) ? out : vbuf;
        reduce_squash_k<<<B_, 256, 0, stream>>>(sp, vout, RS);
        if (it < 2) a_fused_k<<<R_ / 4, 256, 0, stream>>>(x, W, vout, blog);
    }
}